// Round 1
// baseline (731.569 us; speedup 1.0000x reference)
//
#include <hip/hip_runtime.h>

// LIF-with-refractory + per-neuron delay-line read.
// N = B*C*H*W; buffer is [T_BUF, N]; out is [5, N]:
//   out[0]=z_delayed, out[1]=z, out[2]=v_new, out[3]=i_dec, out[4]=rho_new
//
// R3: the per-neuron random-row gather (64 lanes -> 64 different 8MB-apart
// rows per instruction, ~2M uncoalesced 64B requests) is request-throughput /
// latency bound, not bandwidth bound. Replace it with a fully-coalesced scan
// over the 63 live buffer rows + predicated select (v_cmp_eq + v_cndmask per
// element). Traffic becomes a deterministic 504 MB stream, which this chip
// moves at ~6.5 TB/s (calibrated by the harness fills).
//
// Semantics: buffer_new = concat(z, buffer[:-1]) =>
//   z_delayed = (d==0) ? z : buffer[d-1][n]; d in [0,64) so row 63 is dead.
// Math expressions bit-identical to R2 (absmax was 0.0).

__global__ __launch_bounds__(256) void lif_step_kernel(
    const float4* __restrict__ i_new4,
    const float4* __restrict__ v4,
    const float4* __restrict__ i4,
    const float4* __restrict__ rho4,
    const float4* __restrict__ buffer4,   // [T_BUF, n4] in float4 units
    const int4*   __restrict__ delay4,    // [n4]
    float* __restrict__ out,              // [5, N]
    int n4)
{
    // Exact-match float32 arithmetic vs numpy: no fma contraction.
    #pragma clang fp contract(off)

    int t = blockIdx.x * blockDim.x + threadIdx.x;
    if (t >= n4) return;

    // ---- coalesced stream loads (one dwordx4 each, lane-contiguous) ----
    float4 vin = v4[t];
    float4 iin = i4[t];
    float4 rin = rho4[t];
    float4 nin = i_new4[t];
    int4   dl  = delay4[t];

    const float vv[4] = {vin.x, vin.y, vin.z, vin.w};
    const float ii[4] = {iin.x, iin.y, iin.z, iin.w};
    const float rr[4] = {rin.x, rin.y, rin.z, rin.w};
    const float nn[4] = {nin.x, nin.y, nin.z, nin.w};
    const int   dd[4] = {dl.x, dl.y, dl.z, dl.w};

    // ---- LIF pointwise math (identical expressions to R2) ----
    float z[4], vnew[4], idec[4], rnew[4];
    #pragma unroll
    for (int j = 0; j < 4; ++j) {
        float refrac = (rr[j] > 0.0f) ? 1.0f : 0.0f;
        float v_dec  = vv[j] + 0.1f * ((1.0f - refrac) * ((0.0f - vv[j]) + ii[j]));
        float zz     = (v_dec > 1.0f) ? 1.0f : 0.0f;
        z[j]    = zz;
        vnew[j] = (1.0f - zz) * v_dec;
        idec[j] = (ii[j] - 0.2f * ii[j]) + nn[j];
        rnew[j] = (rr[j] - refrac) + zz * 5.0f;          // DT*TAU_REFRAC_INV = 1.0
    }

    // ---- streamed delay-line scan: rows 0..62, predicated select ----
    // d==0 wraps to r0=0xFFFFFFFF which never matches (r <= 62) -> z later.
    const unsigned r0 = (unsigned)dd[0] - 1u;
    const unsigned r1 = (unsigned)dd[1] - 1u;
    const unsigned r2 = (unsigned)dd[2] - 1u;
    const unsigned r3 = (unsigned)dd[3] - 1u;
    float zd0 = 0.0f, zd1 = 0.0f, zd2 = 0.0f, zd3 = 0.0f;

    const float4* bp = buffer4 + t;          // column group t, row 0
    #pragma unroll 7                          // 63 = 9 x 7; keeps 7 loads in flight
    for (unsigned r = 0; r < 63u; ++r) {
        float4 bv = *bp;                      // global_load_dwordx4, coalesced
        bp += n4;                             // next row (stride N floats)
        zd0 = (r == r0) ? bv.x : zd0;         // v_cmp_eq_u32 + v_cndmask
        zd1 = (r == r1) ? bv.y : zd1;
        zd2 = (r == r2) ? bv.z : zd2;
        zd3 = (r == r3) ? bv.w : zd3;
    }
    zd0 = (dd[0] == 0) ? z[0] : zd0;
    zd1 = (dd[1] == 0) ? z[1] : zd1;
    zd2 = (dd[2] == 0) ? z[2] : zd2;
    zd3 = (dd[3] == 0) ? z[3] : zd3;

    // ---- coalesced stores (one dwordx4 per plane) ----
    float4* o = (float4*)out;
    size_t  s = (size_t)n4;
    o[0 * s + t] = make_float4(zd0, zd1, zd2, zd3);
    o[1 * s + t] = make_float4(z[0], z[1], z[2], z[3]);
    o[2 * s + t] = make_float4(vnew[0], vnew[1], vnew[2], vnew[3]);
    o[3 * s + t] = make_float4(idec[0], idec[1], idec[2], idec[3]);
    o[4 * s + t] = make_float4(rnew[0], rnew[1], rnew[2], rnew[3]);
}

extern "C" void kernel_launch(void* const* d_in, const int* in_sizes, int n_in,
                              void* d_out, int out_size, void* d_ws, size_t ws_size,
                              hipStream_t stream) {
    const float* i_new  = (const float*)d_in[0];
    const float* v      = (const float*)d_in[1];
    const float* i_cur  = (const float*)d_in[2];
    const float* rho    = (const float*)d_in[3];
    const float* buffer = (const float*)d_in[4];
    const int*   delay  = (const int*)d_in[5];
    float* out = (float*)d_out;

    int N  = in_sizes[0];          // B*C*H*W (2^21 here)
    int n4 = N >> 2;               // N divisible by 4 (W=64)

    int block = 256;
    int grid  = (n4 + block - 1) / block;   // 2048 WGs -> 8/CU, all resident

    lif_step_kernel<<<grid, block, 0, stream>>>(
        (const float4*)i_new, (const float4*)v, (const float4*)i_cur,
        (const float4*)rho, (const float4*)buffer, (const int4*)delay,
        out, n4);
}